// Round 1
// baseline (789.425 us; speedup 1.0000x reference)
//
#include <hip/hip_runtime.h>
#include <hip/hip_bf16.h>

#define TT 256   // tokens per batch
#define CC 384   // channels
#define HSZ 64   // head size

typedef __attribute__((ext_vector_type(8))) short bf16x8;
typedef __attribute__((ext_vector_type(4))) float f32x4;

static __device__ __forceinline__ unsigned short f2bf(float f) {
    union { __hip_bfloat16 h; unsigned short u; } cv;
    cv.h = __float2bfloat16(f);
    return cv.u;
}

// pack 8 fp32 (two float4) -> bf16x8 (RNE)
static __device__ __forceinline__ bf16x8 cvt8(float4 a, float4 b) {
    bf16x8 r;
    r[0] = (short)f2bf(a.x); r[1] = (short)f2bf(a.y);
    r[2] = (short)f2bf(a.z); r[3] = (short)f2bf(a.w);
    r[4] = (short)f2bf(b.x); r[5] = (short)f2bf(b.y);
    r[6] = (short)f2bf(b.z); r[7] = (short)f2bf(b.w);
    return r;
}

// ---- kernel 1: Wt[n][ck] = bf16(W_{n/64}[ck][n%64])  (n in [0,192), ck in [0,384)) ----
__global__ __launch_bounds__(256) void wtrans_kernel(
        const float* __restrict__ Wq,
        const float* __restrict__ Wk,
        const float* __restrict__ Wv,
        unsigned short* __restrict__ Wt) {
    int idx = blockIdx.x * 256 + threadIdx.x;
    if (idx >= 192 * CC) return;
    int n = idx / CC;
    int ck = idx - n * CC;
    const float* W = (n < 64) ? Wq : ((n < 128) ? Wk : Wv);
    Wt[n * CC + ck] = f2bf(W[ck * HSZ + (n & 63)]);
}

// ---- kernel 2: fused QKV + causal flash attention. One WG (8 waves) per batch. ----
// Phase 1 (two passes, acc[12] only -> <=128 regs -> 4 waves/SIMD): pass t computes
//   q,k,v for 16-row tile {16w, 240-16w}[t]. k -> k_lds[token][hs], v -> v_lds[hs][token],
//   q -> A-frags via per-wave pbuf transpose.
// Phase 2: swapped-QK^T flash attention (S^T = mfma(K,Q)): each lane owns ONE q-row,
//   softmax reductions are lane-local + 2 shfl_xor; PV computed as O^T = mfma(V^T, P^T).
__global__ __launch_bounds__(512, 4) void fused_kernel(
        const float* __restrict__ x,
        const unsigned short* __restrict__ Wt,
        float* __restrict__ outp) {
    __shared__ __align__(16) unsigned short k_lds[TT][72];    // 36 KB
    __shared__ __align__(16) unsigned short v_lds[HSZ][264];  // 33.8 KB
    __shared__ __align__(16) unsigned short pbuf[8][16][40];  // 10 KB, per-wave scratch

    const int b    = blockIdx.x;
    const int lane = threadIdx.x & 63;
    const int w    = threadIdx.x >> 6;   // wave 0..7
    const int c    = lane & 15;
    const int quad = lane >> 4;

    const unsigned short* wb = Wt + c * CC + quad * 8;

    bf16x8 qf[2][2];  // qf[t][ks]: A/B-frag of q rows for tile t (row=c, k=quad*8+j)

    // ---------------- phase 1: QKV projection, two row-tile passes ----------------
    #pragma unroll
    for (int t = 0; t < 2; ++t) {
        const int R = (t == 0) ? 16 * w : 240 - 16 * w;   // tile base row

        f32x4 acc[12];
        #pragma unroll
        for (int n = 0; n < 12; ++n) acc[n] = (f32x4){0.f, 0.f, 0.f, 0.f};

        const float* xa = x + ((size_t)b * TT + R + c) * CC + quad * 8;
        float4 alo = *(const float4*)(xa);
        float4 ahi = *(const float4*)(xa + 4);

        #pragma unroll
        for (int s = 0; s < 12; ++s) {
            bf16x8 a = cvt8(alo, ahi);
            if (s < 11) {  // prefetch next K-slice of x
                alo = *(const float4*)(xa + (s + 1) * 32);
                ahi = *(const float4*)(xa + (s + 1) * 32 + 4);
            }
            #pragma unroll
            for (int n = 0; n < 12; ++n) {
                bf16x8 bfv = *(const bf16x8*)(wb + n * 16 * CC + s * 32);
                acc[n] = __builtin_amdgcn_mfma_f32_16x16x32_bf16(a, bfv, acc[n], 0, 0, 0);
            }
        }

        // epilogue for this tile
        const int lr = R + quad * 4;   // + r gives token row
        // k: n-tiles 4..7 -> k_lds[token][hs]
        #pragma unroll
        for (int n = 4; n < 8; ++n) {
            const int cg = (n - 4) * 16 + c;
            #pragma unroll
            for (int r = 0; r < 4; ++r)
                k_lds[lr + r][cg] = f2bf(acc[n][r]);
        }
        // v: n-tiles 8..11 -> v_lds[hs][token], 4 consecutive tokens packed
        #pragma unroll
        for (int n = 8; n < 12; ++n) {
            const int hsg = (n - 8) * 16 + c;
            ushort4 pk;
            pk.x = f2bf(acc[n][0]);
            pk.y = f2bf(acc[n][1]);
            pk.z = f2bf(acc[n][2]);
            pk.w = f2bf(acc[n][3]);
            *(ushort4*)(&v_lds[hsg][lr]) = pk;
        }
        // q: n-tiles 0..3, C-layout -> pbuf -> A-layout frags (two 32-col passes)
        #pragma unroll
        for (int p = 0; p < 2; ++p) {
            #pragma unroll
            for (int n2 = 0; n2 < 2; ++n2) {
                const int n = 2 * p + n2;
                #pragma unroll
                for (int r = 0; r < 4; ++r)
                    pbuf[w][quad * 4 + r][n2 * 16 + c] = f2bf(acc[n][r]);
            }
            qf[t][p] = *(const bf16x8*)(&pbuf[w][c][quad * 8]);
        }
    }

    __syncthreads();

    // ---------------- phase 2: causal flash attention (swapped QK^T) ----------------
    const int mt0 = w;
    const int mt1 = 15 - w;  // mt1 >= mt0

    // of[ti][n]: O^T accumulator; col(lane&15)=q, row(quad*4+r)=hs within n*16 block
    f32x4 of[2][4];
    float mst[2] = {-1e30f, -1e30f};
    float lst[2] = {0.f, 0.f};
    #pragma unroll
    for (int i = 0; i < 2; ++i)
        #pragma unroll
        for (int n = 0; n < 4; ++n)
            of[i][n] = (f32x4){0.f, 0.f, 0.f, 0.f};

    const float qscale = 0.18033688011112042f;  // (1/sqrt(64)) * log2(e)

    for (int kt = 0; kt < 8; ++kt) {
        if (mt1 < 2 * kt) break;  // both tiles done (wave-uniform)
        const int k0 = kt * 32;

        bf16x8 kf[2][2], vf[4];
        #pragma unroll
        for (int nt = 0; nt < 2; ++nt)
            #pragma unroll
            for (int ks = 0; ks < 2; ++ks)
                kf[nt][ks] = *(const bf16x8*)(&k_lds[k0 + nt * 16 + c][ks * 32 + quad * 8]);
        #pragma unroll
        for (int n = 0; n < 4; ++n)
            vf[n] = *(const bf16x8*)(&v_lds[n * 16 + c][k0 + quad * 8]);

        #pragma unroll
        for (int ti = 0; ti < 2; ++ti) {
            const int mt = ti ? mt1 : mt0;
            if (mt < 2 * kt) continue;
            const int rb = mt * 16;

            // S^T = mfma(K, Q): lane holds q = rb + c, keys k0 + nt*16 + quad*4 + r
            f32x4 s0 = {0.f, 0.f, 0.f, 0.f}, s1 = {0.f, 0.f, 0.f, 0.f};
            #pragma unroll
            for (int ks = 0; ks < 2; ++ks) {
                s0 = __builtin_amdgcn_mfma_f32_16x16x32_bf16(kf[0][ks], qf[ti][ks], s0, 0, 0, 0);
                s1 = __builtin_amdgcn_mfma_f32_16x16x32_bf16(kf[1][ks], qf[ti][ks], s1, 0, 0, 0);
            }

            float t0[4], t1[4];
            #pragma unroll
            for (int r = 0; r < 4; ++r) { t0[r] = s0[r] * qscale; t1[r] = s1[r] * qscale; }

            if (mt < 2 * kt + 2) {  // diagonal-adjacent: causal mask (k > q)
                #pragma unroll
                for (int r = 0; r < 4; ++r) {
                    const int kk = k0 + quad * 4 + r;
                    if (kk > rb + c)      t0[r] = -1e30f;
                    if (kk + 16 > rb + c) t1[r] = -1e30f;
                }
            }

            // row max: 8 in-register values, then across quads (k lives on quads)
            float mx = fmaxf(fmaxf(fmaxf(t0[0], t0[1]), fmaxf(t0[2], t0[3])),
                             fmaxf(fmaxf(t1[0], t1[1]), fmaxf(t1[2], t1[3])));
            mx = fmaxf(mx, __shfl_xor(mx, 16, 64));
            mx = fmaxf(mx, __shfl_xor(mx, 32, 64));

            const float mnew  = fmaxf(mst[ti], mx);
            const float alpha = exp2f(mst[ti] - mnew);
            mst[ti] = mnew;

            float p0[4], p1[4];
            float rs = 0.f;
            #pragma unroll
            for (int r = 0; r < 4; ++r) {
                p0[r] = exp2f(t0[r] - mnew);
                p1[r] = exp2f(t1[r] - mnew);
                rs += p0[r] + p1[r];
            }
            rs += __shfl_xor(rs, 16, 64);
            rs += __shfl_xor(rs, 32, 64);
            lst[ti] = lst[ti] * alpha + rs;

            #pragma unroll
            for (int n = 0; n < 4; ++n)
                #pragma unroll
                for (int r = 0; r < 4; ++r)
                    of[ti][n][r] *= alpha;

            // P[q][k] -> pbuf[q][k]: lane writes its 8 keys as two packed b64
            ushort4 pk0, pk1;
            pk0.x = f2bf(p0[0]); pk0.y = f2bf(p0[1]); pk0.z = f2bf(p0[2]); pk0.w = f2bf(p0[3]);
            pk1.x = f2bf(p1[0]); pk1.y = f2bf(p1[1]); pk1.z = f2bf(p1[2]); pk1.w = f2bf(p1[3]);
            *(ushort4*)(&pbuf[w][c][quad * 4])      = pk0;
            *(ushort4*)(&pbuf[w][c][16 + quad * 4]) = pk1;
            // B-frag of P^T: col(lane&15)=q, k=quad*8+j
            bf16x8 pf = *(const bf16x8*)(&pbuf[w][c][quad * 8]);

            // O^T += V^T * P^T  (vf already has A-layout: row=hs, k=token)
            #pragma unroll
            for (int n = 0; n < 4; ++n)
                of[ti][n] = __builtin_amdgcn_mfma_f32_16x16x32_bf16(vf[n], pf, of[ti][n], 0, 0, 0);
        }
    }

    // epilogue: normalize (scalar per lane) and store O via packed float4
    float* ob = outp + (size_t)b * TT * HSZ;
    #pragma unroll
    for (int ti = 0; ti < 2; ++ti) {
        const int rb = (ti ? mt1 : mt0) * 16;
        const float inv = 1.f / lst[ti];
        #pragma unroll
        for (int n = 0; n < 4; ++n) {
            float4 st;
            st.x = of[ti][n][0] * inv;
            st.y = of[ti][n][1] * inv;
            st.z = of[ti][n][2] * inv;
            st.w = of[ti][n][3] * inv;
            *(float4*)(ob + (size_t)(rb + c) * HSZ + n * 16 + quad * 4) = st;
        }
    }
}

extern "C" void kernel_launch(void* const* d_in, const int* in_sizes, int n_in,
                              void* d_out, int out_size, void* d_ws, size_t ws_size,
                              hipStream_t stream) {
    const float* x  = (const float*)d_in[0];
    const float* Wq = (const float*)d_in[1];
    const float* Wk = (const float*)d_in[2];
    const float* Wv = (const float*)d_in[3];
    float* outp = (float*)d_out;

    const int Bn = in_sizes[0] / (TT * CC);  // 1024

    unsigned short* Wt = (unsigned short*)d_ws;  // 147456 B used

    hipLaunchKernelGGL(wtrans_kernel, dim3(288), dim3(256), 0, stream, Wq, Wk, Wv, Wt);
    hipLaunchKernelGGL(fused_kernel, dim3(Bn), dim3(512), 0, stream, x, Wt, outp);
}

// Round 3
// 665.878 us; speedup vs baseline: 1.1855x; 1.1855x over previous
//
#include <hip/hip_runtime.h>
#include <hip/hip_bf16.h>

#define TT 256   // tokens per batch
#define CC 384   // channels
#define HSZ 64   // head size

typedef __attribute__((ext_vector_type(8))) short bf16x8;
typedef __attribute__((ext_vector_type(4))) float f32x4;

static __device__ __forceinline__ unsigned short f2bf(float f) {
    union { __hip_bfloat16 h; unsigned short u; } cv;
    cv.h = __float2bfloat16(f);
    return cv.u;
}

// pack 8 fp32 (two float4) -> bf16x8 (RNE)
static __device__ __forceinline__ bf16x8 cvt8(float4 a, float4 b) {
    bf16x8 r;
    r[0] = (short)f2bf(a.x); r[1] = (short)f2bf(a.y);
    r[2] = (short)f2bf(a.z); r[3] = (short)f2bf(a.w);
    r[4] = (short)f2bf(b.x); r[5] = (short)f2bf(b.y);
    r[6] = (short)f2bf(b.z); r[7] = (short)f2bf(b.w);
    return r;
}

// ---- kernel 1: Wt[n][ck] = bf16(W_{n/64}[ck][n%64])  (n in [0,192), ck in [0,384)) ----
__global__ __launch_bounds__(256) void wtrans_kernel(
        const float* __restrict__ Wq,
        const float* __restrict__ Wk,
        const float* __restrict__ Wv,
        unsigned short* __restrict__ Wt) {
    int idx = blockIdx.x * 256 + threadIdx.x;
    if (idx >= 192 * CC) return;
    int n = idx / CC;
    int ck = idx - n * CC;
    const float* W = (n < 64) ? Wq : ((n < 128) ? Wk : Wv);
    Wt[n * CC + ck] = f2bf(W[ck * HSZ + (n & 63)]);
}

// ---- kernel 2: fused QKV + causal flash attention. One WG (8 waves) per batch. ----
// Phase 1: BOTH 16-row tiles in one fully-unrolled K-loop (24 MFMA per x-slice, max ILP)
//   with an explicit depth-2 software pipeline on the x loads (named regs, static idx).
//   k -> k_lds[token][hs], v -> v_lds[hs][token], q -> A-frags via per-wave pbuf.
// Phase 2: swapped-QK^T flash attention (S^T = mfma(K,Q)): each lane owns ONE q-row,
//   softmax reductions are lane-local + 2 shfl_xor; PV computed as O^T = mfma(V^T, P^T).
__global__ __launch_bounds__(512, 2) void fused_kernel(
        const float* __restrict__ x,
        const unsigned short* __restrict__ Wt,
        float* __restrict__ outp) {
    __shared__ __align__(16) unsigned short k_lds[TT][72];    // 36 KB
    __shared__ __align__(16) unsigned short v_lds[HSZ][264];  // 33.8 KB
    __shared__ __align__(16) unsigned short pbuf[8][16][40];  // 10 KB, per-wave scratch

    const int b    = blockIdx.x;
    const int lane = threadIdx.x & 63;
    const int w    = threadIdx.x >> 6;   // wave 0..7
    const int c    = lane & 15;
    const int quad = lane >> 4;

    const int Rl0 = 16 * w;        // tile 0 rows (m-tile w)
    const int Rl1 = 240 - 16 * w;  // tile 1 rows (m-tile 15-w)

    // ---------------- phase 1: QKV projection (two tiles, pipelined x) ----------------
    f32x4 acc[2][12];
    #pragma unroll
    for (int t = 0; t < 2; ++t)
        #pragma unroll
        for (int n = 0; n < 12; ++n)
            acc[t][n] = (f32x4){0.f, 0.f, 0.f, 0.f};

    const float* xa0 = x + ((size_t)b * TT + Rl0 + c) * CC + quad * 8;
    const float* xa1 = x + ((size_t)b * TT + Rl1 + c) * CC + quad * 8;
    const unsigned short* wb = Wt + c * CC + quad * 8;

    // depth-2 x pipeline: A* = slice s (current), B* = slice s+1 (in flight)
    float4 A0lo = *(const float4*)(xa0);
    float4 A0hi = *(const float4*)(xa0 + 4);
    float4 A1lo = *(const float4*)(xa1);
    float4 A1hi = *(const float4*)(xa1 + 4);
    float4 B0lo = *(const float4*)(xa0 + 32);
    float4 B0hi = *(const float4*)(xa0 + 36);
    float4 B1lo = *(const float4*)(xa1 + 32);
    float4 B1hi = *(const float4*)(xa1 + 36);

    #pragma unroll
    for (int s = 0; s < 12; ++s) {
        bf16x8 a0 = cvt8(A0lo, A0hi);
        bf16x8 a1 = cvt8(A1lo, A1hi);
        // rotate pipeline (register renames under full unroll)
        A0lo = B0lo; A0hi = B0hi; A1lo = B1lo; A1hi = B1hi;
        if (s < 10) {  // issue loads for slice s+2 (full iteration of cover)
            B0lo = *(const float4*)(xa0 + (s + 2) * 32);
            B0hi = *(const float4*)(xa0 + (s + 2) * 32 + 4);
            B1lo = *(const float4*)(xa1 + (s + 2) * 32);
            B1hi = *(const float4*)(xa1 + (s + 2) * 32 + 4);
        }
        #pragma unroll
        for (int n = 0; n < 12; ++n) {
            bf16x8 bfv = *(const bf16x8*)(wb + n * 16 * CC + s * 32);
            acc[0][n] = __builtin_amdgcn_mfma_f32_16x16x32_bf16(a0, bfv, acc[0][n], 0, 0, 0);
            acc[1][n] = __builtin_amdgcn_mfma_f32_16x16x32_bf16(a1, bfv, acc[1][n], 0, 0, 0);
        }
    }

    // epilogue: scatter k, v to LDS; transpose q to A-frags via per-wave pbuf
    bf16x8 qf[2][2];
    #pragma unroll
    for (int t = 0; t < 2; ++t) {
        const int lr = (t == 0 ? Rl0 : Rl1) + quad * 4;  // + r gives local token row
        // k: n-tiles 4..7 -> k_lds[token][hs]
        #pragma unroll
        for (int n = 4; n < 8; ++n) {
            const int cg = (n - 4) * 16 + c;
            #pragma unroll
            for (int r = 0; r < 4; ++r)
                k_lds[lr + r][cg] = f2bf(acc[t][n][r]);
        }
        // v: n-tiles 8..11 -> v_lds[hs][token], 4 consecutive tokens packed
        #pragma unroll
        for (int n = 8; n < 12; ++n) {
            const int hsg = (n - 8) * 16 + c;
            ushort4 pk;
            pk.x = f2bf(acc[t][n][0]);
            pk.y = f2bf(acc[t][n][1]);
            pk.z = f2bf(acc[t][n][2]);
            pk.w = f2bf(acc[t][n][3]);
            *(ushort4*)(&v_lds[hsg][lr]) = pk;
        }
        // q: n-tiles 0..3, C-layout -> pbuf -> A-layout frags (two 32-col passes)
        #pragma unroll
        for (int p = 0; p < 2; ++p) {
            #pragma unroll
            for (int n2 = 0; n2 < 2; ++n2) {
                const int n = 2 * p + n2;
                #pragma unroll
                for (int r = 0; r < 4; ++r)
                    pbuf[w][quad * 4 + r][n2 * 16 + c] = f2bf(acc[t][n][r]);
            }
            qf[t][p] = *(const bf16x8*)(&pbuf[w][c][quad * 8]);
        }
    }

    __syncthreads();

    // ---------------- phase 2: causal flash attention (swapped QK^T) ----------------
    const int mt0 = w;
    const int mt1 = 15 - w;  // mt1 >= mt0

    // of[ti][n]: O^T accumulator; col(lane&15)=q, row(quad*4+r)=hs within n*16 block
    f32x4 of[2][4];
    float mst[2] = {-1e30f, -1e30f};
    float lst[2] = {0.f, 0.f};
    #pragma unroll
    for (int i = 0; i < 2; ++i)
        #pragma unroll
        for (int n = 0; n < 4; ++n)
            of[i][n] = (f32x4){0.f, 0.f, 0.f, 0.f};

    const float qscale = 0.18033688011112042f;  // (1/sqrt(64)) * log2(e)

    for (int kt = 0; kt < 8; ++kt) {
        if (mt1 < 2 * kt) break;  // both tiles done (wave-uniform)
        const int k0 = kt * 32;

        bf16x8 kf[2][2], vf[4];
        #pragma unroll
        for (int nt = 0; nt < 2; ++nt)
            #pragma unroll
            for (int ks = 0; ks < 2; ++ks)
                kf[nt][ks] = *(const bf16x8*)(&k_lds[k0 + nt * 16 + c][ks * 32 + quad * 8]);
        #pragma unroll
        for (int n = 0; n < 4; ++n)
            vf[n] = *(const bf16x8*)(&v_lds[n * 16 + c][k0 + quad * 8]);

        #pragma unroll
        for (int ti = 0; ti < 2; ++ti) {
            const int mt = ti ? mt1 : mt0;
            if (mt < 2 * kt) continue;
            const int rb = mt * 16;

            // S^T = mfma(K, Q): lane holds q = rb + c, keys k0 + nt*16 + quad*4 + r
            f32x4 s0 = {0.f, 0.f, 0.f, 0.f}, s1 = {0.f, 0.f, 0.f, 0.f};
            #pragma unroll
            for (int ks = 0; ks < 2; ++ks) {
                s0 = __builtin_amdgcn_mfma_f32_16x16x32_bf16(kf[0][ks], qf[ti][ks], s0, 0, 0, 0);
                s1 = __builtin_amdgcn_mfma_f32_16x16x32_bf16(kf[1][ks], qf[ti][ks], s1, 0, 0, 0);
            }

            float t0[4], t1[4];
            #pragma unroll
            for (int r = 0; r < 4; ++r) { t0[r] = s0[r] * qscale; t1[r] = s1[r] * qscale; }

            if (mt < 2 * kt + 2) {  // diagonal-adjacent: causal mask (k > q)
                #pragma unroll
                for (int r = 0; r < 4; ++r) {
                    const int kk = k0 + quad * 4 + r;
                    if (kk > rb + c)      t0[r] = -1e30f;
                    if (kk + 16 > rb + c) t1[r] = -1e30f;
                }
            }

            // row max: 8 in-register values, then across quads (k lives on quads)
            float mx = fmaxf(fmaxf(fmaxf(t0[0], t0[1]), fmaxf(t0[2], t0[3])),
                             fmaxf(fmaxf(t1[0], t1[1]), fmaxf(t1[2], t1[3])));
            mx = fmaxf(mx, __shfl_xor(mx, 16, 64));
            mx = fmaxf(mx, __shfl_xor(mx, 32, 64));

            const float mnew  = fmaxf(mst[ti], mx);
            const float alpha = exp2f(mst[ti] - mnew);
            mst[ti] = mnew;

            float p0[4], p1[4];
            float rs = 0.f;
            #pragma unroll
            for (int r = 0; r < 4; ++r) {
                p0[r] = exp2f(t0[r] - mnew);
                p1[r] = exp2f(t1[r] - mnew);
                rs += p0[r] + p1[r];
            }
            rs += __shfl_xor(rs, 16, 64);
            rs += __shfl_xor(rs, 32, 64);
            lst[ti] = lst[ti] * alpha + rs;

            #pragma unroll
            for (int n = 0; n < 4; ++n)
                #pragma unroll
                for (int r = 0; r < 4; ++r)
                    of[ti][n][r] *= alpha;

            // P[q][k] -> pbuf[q][k]: lane writes its 8 keys as two packed b64
            ushort4 pk0, pk1;
            pk0.x = f2bf(p0[0]); pk0.y = f2bf(p0[1]); pk0.z = f2bf(p0[2]); pk0.w = f2bf(p0[3]);
            pk1.x = f2bf(p1[0]); pk1.y = f2bf(p1[1]); pk1.z = f2bf(p1[2]); pk1.w = f2bf(p1[3]);
            *(ushort4*)(&pbuf[w][c][quad * 4])      = pk0;
            *(ushort4*)(&pbuf[w][c][16 + quad * 4]) = pk1;
            // B-frag of P^T: col(lane&15)=q, k=quad*8+j
            bf16x8 pf = *(const bf16x8*)(&pbuf[w][c][quad * 8]);

            // O^T += V^T * P^T  (vf already has A-layout: row=hs, k=token)
            #pragma unroll
            for (int n = 0; n < 4; ++n)
                of[ti][n] = __builtin_amdgcn_mfma_f32_16x16x32_bf16(vf[n], pf, of[ti][n], 0, 0, 0);
        }
    }

    // epilogue: normalize (scalar per lane) and store O via packed float4
    float* ob = outp + (size_t)b * TT * HSZ;
    #pragma unroll
    for (int ti = 0; ti < 2; ++ti) {
        const int rb = (ti ? mt1 : mt0) * 16;
        const float inv = 1.f / lst[ti];
        #pragma unroll
        for (int n = 0; n < 4; ++n) {
            float4 st;
            st.x = of[ti][n][0] * inv;
            st.y = of[ti][n][1] * inv;
            st.z = of[ti][n][2] * inv;
            st.w = of[ti][n][3] * inv;
            *(float4*)(ob + (size_t)(rb + c) * HSZ + n * 16 + quad * 4) = st;
        }
    }
}

extern "C" void kernel_launch(void* const* d_in, const int* in_sizes, int n_in,
                              void* d_out, int out_size, void* d_ws, size_t ws_size,
                              hipStream_t stream) {
    const float* x  = (const float*)d_in[0];
    const float* Wq = (const float*)d_in[1];
    const float* Wk = (const float*)d_in[2];
    const float* Wv = (const float*)d_in[3];
    float* outp = (float*)d_out;

    const int Bn = in_sizes[0] / (TT * CC);  // 1024

    unsigned short* Wt = (unsigned short*)d_ws;  // 147456 B used

    hipLaunchKernelGGL(wtrans_kernel, dim3(288), dim3(256), 0, stream, Wq, Wk, Wv, Wt);
    hipLaunchKernelGGL(fused_kernel, dim3(Bn), dim3(512), 0, stream, x, Wt, outp);
}

// Round 4
// 576.996 us; speedup vs baseline: 1.3682x; 1.1540x over previous
//
#include <hip/hip_runtime.h>
#include <hip/hip_bf16.h>

#define TT 256   // tokens per batch
#define CC 384   // channels
#define HSZ 64   // head size

typedef __attribute__((ext_vector_type(8))) short bf16x8;
typedef __attribute__((ext_vector_type(4))) float f32x4;

static __device__ __forceinline__ unsigned short f2bf(float f) {
    union { __hip_bfloat16 h; unsigned short u; } cv;
    cv.h = __float2bfloat16(f);
    return cv.u;
}

// pack 8 fp32 (two float4) -> bf16x8 (RNE)
static __device__ __forceinline__ bf16x8 cvt8(float4 a, float4 b) {
    bf16x8 r;
    r[0] = (short)f2bf(a.x); r[1] = (short)f2bf(a.y);
    r[2] = (short)f2bf(a.z); r[3] = (short)f2bf(a.w);
    r[4] = (short)f2bf(b.x); r[5] = (short)f2bf(b.y);
    r[6] = (short)f2bf(b.z); r[7] = (short)f2bf(b.w);
    return r;
}

// ---- kernel 1: Wt[n][ck] = bf16(W_{n/64}[ck][n%64])  (n in [0,192), ck in [0,384)) ----
__global__ __launch_bounds__(256) void wtrans_kernel(
        const float* __restrict__ Wq,
        const float* __restrict__ Wk,
        const float* __restrict__ Wv,
        unsigned short* __restrict__ Wt) {
    int idx = blockIdx.x * 256 + threadIdx.x;
    if (idx >= 192 * CC) return;
    int n = idx / CC;
    int ck = idx - n * CC;
    const float* W = (n < 64) ? Wq : ((n < 128) ? Wk : Wv);
    Wt[n * CC + ck] = f2bf(W[ck * HSZ + (n & 63)]);
}

// ---- kernel 2: fused QKV + causal flash attention. One WG (8 waves) per batch. ----
// Phase 1 (queue-decoupled pipeline):
//   - Wt staged to LDS in 2-slice granules via global_load_lds (double-buffered,
//     XOR-swizzled source so column-slice ds_read_b128 is conflict-free).
//     Inner-loop B reads are lgkm -> never drain the x vmcnt queue.
//   - x streamed to registers with a depth-3 ring (static idx under full unroll):
//     ~3 iterations (>900 cy) of latency cover; 12 KB/wave in flight.
//   - vmcnt(0) drains only at 6 granule barriers.
// Phase 2: swapped-QK^T flash attention (lane-local softmax), unchanged.
__global__ __launch_bounds__(512, 2) void fused_kernel(
        const float* __restrict__ x,
        const unsigned short* __restrict__ Wt,
        float* __restrict__ outp) {
    __shared__ __align__(16) unsigned short wtb[2][192][64];  // 48 KB: Wt granule dbuf
    __shared__ __align__(16) unsigned short k_lds[TT][72];    // 36 KB
    __shared__ __align__(16) unsigned short v_lds[HSZ][264];  // 33.8 KB
    __shared__ __align__(16) unsigned short pbuf[8][16][40];  // 10 KB, per-wave scratch
    // total 130048 B

    const int b    = blockIdx.x;
    const int lane = threadIdx.x & 63;
    const int w    = threadIdx.x >> 6;   // wave 0..7
    const int c    = lane & 15;
    const int quad = lane >> 4;

    const int Rl0 = 16 * w;        // tile 0 rows (m-tile w)
    const int Rl1 = 240 - 16 * w;  // tile 1 rows (m-tile 15-w)

    // ---- Wt granule staging: granule g = k-slices {2g, 2g+1} (64 cols bf16 = 128 B/row).
    // LDS dest is linear (wave-uniform base + lane*16, hw-implied). Position (row, P)
    // holds global k-slot (P ^ (row&7)) -> readers use slot' = slot ^ (row&7). 2-way max.
    auto stage_wt = [&](int g) {
        unsigned short* dst = &wtb[g & 1][0][0];
        #pragma unroll
        for (int i = 0; i < 3; ++i) {
            const int base = w * 3072 + i * 1024;        // wave-uniform byte base
            const int off  = base + lane * 16;           // this lane's dest byte
            const int row  = off >> 7;                   // n-row 0..191
            const int P    = (off >> 4) & 7;             // 16B slot within row
            const unsigned short* src = Wt + row * CC + g * 64 + ((P ^ (row & 7)) * 8);
            __builtin_amdgcn_global_load_lds(
                (const __attribute__((address_space(1))) unsigned int*)(const void*)src,
                (__attribute__((address_space(3))) unsigned int*)(void*)(dst + (base >> 1)),
                16, 0, 0);
        }
    };

    // ---------------- phase 1: QKV projection ----------------
    const float* xa0 = x + ((size_t)b * TT + Rl0 + c) * CC + quad * 8;
    const float* xa1 = x + ((size_t)b * TT + Rl1 + c) * CC + quad * 8;

    stage_wt(0);

    // depth-3 x ring: X[s%3] holds slice s (2 tiles x lo/hi float4)
    float4 X[3][4];
    #pragma unroll
    for (int i = 0; i < 3; ++i) {
        X[i][0] = *(const float4*)(xa0 + i * 32);
        X[i][1] = *(const float4*)(xa0 + i * 32 + 4);
        X[i][2] = *(const float4*)(xa1 + i * 32);
        X[i][3] = *(const float4*)(xa1 + i * 32 + 4);
    }

    f32x4 acc[2][12];
    #pragma unroll
    for (int t = 0; t < 2; ++t)
        #pragma unroll
        for (int n = 0; n < 12; ++n)
            acc[t][n] = (f32x4){0.f, 0.f, 0.f, 0.f};

    __syncthreads();  // granule 0 staged

    #pragma unroll
    for (int s = 0; s < 12; ++s) {
        if (s >= 2 && (s & 1) == 0) __syncthreads();   // granule s/2 ready; prev reads done
        if ((s & 1) == 0 && s <= 8) stage_wt(s / 2 + 1);

        // consume slice s BEFORE refilling its ring slot
        bf16x8 a0 = cvt8(X[s % 3][0], X[s % 3][1]);
        bf16x8 a1 = cvt8(X[s % 3][2], X[s % 3][3]);
        if (s + 3 < 12) {
            X[s % 3][0] = *(const float4*)(xa0 + (s + 3) * 32);
            X[s % 3][1] = *(const float4*)(xa0 + (s + 3) * 32 + 4);
            X[s % 3][2] = *(const float4*)(xa1 + (s + 3) * 32);
            X[s % 3][3] = *(const float4*)(xa1 + (s + 3) * 32 + 4);
        }

        const int g = s >> 1, p = s & 1;
        #pragma unroll
        for (int n = 0; n < 12; ++n) {
            const int row  = n * 16 + c;
            const int slot = (p * 4 + quad) ^ (c & 7);
            bf16x8 bfv = *(const bf16x8*)(&wtb[g & 1][row][slot * 8]);
            acc[0][n] = __builtin_amdgcn_mfma_f32_16x16x32_bf16(a0, bfv, acc[0][n], 0, 0, 0);
            acc[1][n] = __builtin_amdgcn_mfma_f32_16x16x32_bf16(a1, bfv, acc[1][n], 0, 0, 0);
        }
    }

    // epilogue: scatter k, v to LDS; transpose q to A-frags via per-wave pbuf
    bf16x8 qf[2][2];
    #pragma unroll
    for (int t = 0; t < 2; ++t) {
        const int lr = (t == 0 ? Rl0 : Rl1) + quad * 4;  // + r gives local token row
        // k: n-tiles 4..7 -> k_lds[token][hs]
        #pragma unroll
        for (int n = 4; n < 8; ++n) {
            const int cg = (n - 4) * 16 + c;
            #pragma unroll
            for (int r = 0; r < 4; ++r)
                k_lds[lr + r][cg] = f2bf(acc[t][n][r]);
        }
        // v: n-tiles 8..11 -> v_lds[hs][token], 4 consecutive tokens packed
        #pragma unroll
        for (int n = 8; n < 12; ++n) {
            const int hsg = (n - 8) * 16 + c;
            ushort4 pk;
            pk.x = f2bf(acc[t][n][0]);
            pk.y = f2bf(acc[t][n][1]);
            pk.z = f2bf(acc[t][n][2]);
            pk.w = f2bf(acc[t][n][3]);
            *(ushort4*)(&v_lds[hsg][lr]) = pk;
        }
        // q: n-tiles 0..3, C-layout -> pbuf -> A-layout frags (two 32-col passes)
        #pragma unroll
        for (int p = 0; p < 2; ++p) {
            #pragma unroll
            for (int n2 = 0; n2 < 2; ++n2) {
                const int n = 2 * p + n2;
                #pragma unroll
                for (int r = 0; r < 4; ++r)
                    pbuf[w][quad * 4 + r][n2 * 16 + c] = f2bf(acc[t][n][r]);
            }
            qf[t][p] = *(const bf16x8*)(&pbuf[w][c][quad * 8]);
        }
    }

    __syncthreads();

    // ---------------- phase 2: causal flash attention (swapped QK^T) ----------------
    const int mt0 = w;
    const int mt1 = 15 - w;  // mt1 >= mt0

    // of[ti][n]: O^T accumulator; col(lane&15)=q, row(quad*4+r)=hs within n*16 block
    f32x4 of[2][4];
    float mst[2] = {-1e30f, -1e30f};
    float lst[2] = {0.f, 0.f};
    #pragma unroll
    for (int i = 0; i < 2; ++i)
        #pragma unroll
        for (int n = 0; n < 4; ++n)
            of[i][n] = (f32x4){0.f, 0.f, 0.f, 0.f};

    const float qscale = 0.18033688011112042f;  // (1/sqrt(64)) * log2(e)

    for (int kt = 0; kt < 8; ++kt) {
        if (mt1 < 2 * kt) break;  // both tiles done (wave-uniform)
        const int k0 = kt * 32;

        bf16x8 kf[2][2], vf[4];
        #pragma unroll
        for (int nt = 0; nt < 2; ++nt)
            #pragma unroll
            for (int ks = 0; ks < 2; ++ks)
                kf[nt][ks] = *(const bf16x8*)(&k_lds[k0 + nt * 16 + c][ks * 32 + quad * 8]);
        #pragma unroll
        for (int n = 0; n < 4; ++n)
            vf[n] = *(const bf16x8*)(&v_lds[n * 16 + c][k0 + quad * 8]);

        #pragma unroll
        for (int ti = 0; ti < 2; ++ti) {
            const int mt = ti ? mt1 : mt0;
            if (mt < 2 * kt) continue;
            const int rb = mt * 16;

            // S^T = mfma(K, Q): lane holds q = rb + c, keys k0 + nt*16 + quad*4 + r
            f32x4 s0 = {0.f, 0.f, 0.f, 0.f}, s1 = {0.f, 0.f, 0.f, 0.f};
            #pragma unroll
            for (int ks = 0; ks < 2; ++ks) {
                s0 = __builtin_amdgcn_mfma_f32_16x16x32_bf16(kf[0][ks], qf[ti][ks], s0, 0, 0, 0);
                s1 = __builtin_amdgcn_mfma_f32_16x16x32_bf16(kf[1][ks], qf[ti][ks], s1, 0, 0, 0);
            }

            float t0[4], t1[4];
            #pragma unroll
            for (int r = 0; r < 4; ++r) { t0[r] = s0[r] * qscale; t1[r] = s1[r] * qscale; }

            if (mt < 2 * kt + 2) {  // diagonal-adjacent: causal mask (k > q)
                #pragma unroll
                for (int r = 0; r < 4; ++r) {
                    const int kk = k0 + quad * 4 + r;
                    if (kk > rb + c)      t0[r] = -1e30f;
                    if (kk + 16 > rb + c) t1[r] = -1e30f;
                }
            }

            // row max: 8 in-register values, then across quads (k lives on quads)
            float mx = fmaxf(fmaxf(fmaxf(t0[0], t0[1]), fmaxf(t0[2], t0[3])),
                             fmaxf(fmaxf(t1[0], t1[1]), fmaxf(t1[2], t1[3])));
            mx = fmaxf(mx, __shfl_xor(mx, 16, 64));
            mx = fmaxf(mx, __shfl_xor(mx, 32, 64));

            const float mnew  = fmaxf(mst[ti], mx);
            const float alpha = exp2f(mst[ti] - mnew);
            mst[ti] = mnew;

            float p0[4], p1[4];
            float rs = 0.f;
            #pragma unroll
            for (int r = 0; r < 4; ++r) {
                p0[r] = exp2f(t0[r] - mnew);
                p1[r] = exp2f(t1[r] - mnew);
                rs += p0[r] + p1[r];
            }
            rs += __shfl_xor(rs, 16, 64);
            rs += __shfl_xor(rs, 32, 64);
            lst[ti] = lst[ti] * alpha + rs;

            #pragma unroll
            for (int n = 0; n < 4; ++n)
                #pragma unroll
                for (int r = 0; r < 4; ++r)
                    of[ti][n][r] *= alpha;

            // P[q][k] -> pbuf[q][k]: lane writes its 8 keys as two packed b64
            ushort4 pk0, pk1;
            pk0.x = f2bf(p0[0]); pk0.y = f2bf(p0[1]); pk0.z = f2bf(p0[2]); pk0.w = f2bf(p0[3]);
            pk1.x = f2bf(p1[0]); pk1.y = f2bf(p1[1]); pk1.z = f2bf(p1[2]); pk1.w = f2bf(p1[3]);
            *(ushort4*)(&pbuf[w][c][quad * 4])      = pk0;
            *(ushort4*)(&pbuf[w][c][16 + quad * 4]) = pk1;
            // B-frag of P^T: col(lane&15)=q, k=quad*8+j
            bf16x8 pf = *(const bf16x8*)(&pbuf[w][c][quad * 8]);

            // O^T += V^T * P^T  (vf already has A-layout: row=hs, k=token)
            #pragma unroll
            for (int n = 0; n < 4; ++n)
                of[ti][n] = __builtin_amdgcn_mfma_f32_16x16x32_bf16(vf[n], pf, of[ti][n], 0, 0, 0);
        }
    }

    // epilogue: normalize (scalar per lane) and store O via packed float4
    float* ob = outp + (size_t)b * TT * HSZ;
    #pragma unroll
    for (int ti = 0; ti < 2; ++ti) {
        const int rb = (ti ? mt1 : mt0) * 16;
        const float inv = 1.f / lst[ti];
        #pragma unroll
        for (int n = 0; n < 4; ++n) {
            float4 st;
            st.x = of[ti][n][0] * inv;
            st.y = of[ti][n][1] * inv;
            st.z = of[ti][n][2] * inv;
            st.w = of[ti][n][3] * inv;
            *(float4*)(ob + (size_t)(rb + c) * HSZ + n * 16 + quad * 4) = st;
        }
    }
}

extern "C" void kernel_launch(void* const* d_in, const int* in_sizes, int n_in,
                              void* d_out, int out_size, void* d_ws, size_t ws_size,
                              hipStream_t stream) {
    const float* x  = (const float*)d_in[0];
    const float* Wq = (const float*)d_in[1];
    const float* Wk = (const float*)d_in[2];
    const float* Wv = (const float*)d_in[3];
    float* outp = (float*)d_out;

    const int Bn = in_sizes[0] / (TT * CC);  // 1024

    unsigned short* Wt = (unsigned short*)d_ws;  // 147456 B used

    hipLaunchKernelGGL(wtrans_kernel, dim3(288), dim3(256), 0, stream, Wq, Wk, Wv, Wt);
    hipLaunchKernelGGL(fused_kernel, dim3(Bn), dim3(512), 0, stream, x, Wt, outp);
}